// Round 1
// baseline (18161.557 us; speedup 1.0000x reference)
//
#include <hip/hip_runtime.h>

// 2-layer LSTM (B=64, T=2048, H=256) as a single persistent cooperative kernel.
// 32 WGs x 256 threads; WG w owns hidden dims [8w, 8w+8) of BOTH layers.
// Recurrent weights live in VGPRs as bf16 MFMA fragments (loaded once).
// Pipeline: phase p computes L0 step p, L1 step p-1, FC output step p-2.
// One inter-WG barrier per phase via step-stamped flags in d_ws.

#define NWG 32
#define BB 64
#define TT 2048
#define HH 256
#define HS 8    // hidden dims per WG per layer
#define RS 32   // gate rows per WG per layer (4*HS)

typedef float  f32x4  __attribute__((ext_vector_type(4)));
typedef __bf16 bf16x8 __attribute__((ext_vector_type(8)));

__device__ __forceinline__ float sigf(float x)   { return 1.0f / (1.0f + __expf(-x)); }
__device__ __forceinline__ float tanh_f(float x) { return 2.0f / (1.0f + __expf(-2.0f * x)) - 1.0f; }

__global__ __launch_bounds__(256, 1) void lstm2_persistent(
    const float* __restrict__ y,
    const float* __restrict__ Wih0, const float* __restrict__ Whh0,
    const float* __restrict__ bih0, const float* __restrict__ bhh0,
    const float* __restrict__ Wih1, const float* __restrict__ Whh1,
    const float* __restrict__ bih1, const float* __restrict__ bhh1,
    const float* __restrict__ Wfc,  const float* __restrict__ bfc,
    float* __restrict__ out,
    __bf16* __restrict__ h0buf,   // [2][BB][HH] bf16, parity-double-buffered
    __bf16* __restrict__ h1buf,   // [2][BB][HH] bf16
    int* __restrict__ flags)      // [NWG] step stamps (poison 0xAA.. < 0 is safe)
{
  const int w    = blockIdx.x;
  const int tid  = threadIdx.x;
  const int wave = tid >> 6;
  const int lane = tid & 63;
  const int ml   = lane & 15;   // row-within-tile for A, col (gate row) for B
  const int kq   = lane >> 4;   // k-quad

  __shared__ float lds_g0[RS][BB + 4];
  __shared__ float lds_g1[RS][BB + 4];
  __shared__ float s_wih0[RS][4];
  __shared__ float s_b0[RS];
  __shared__ float s_b1[RS];

  // ---- load recurrent weights into per-wave VGPR B-fragments (bf16) ----
  // slice row r (0..31): gate = r>>3 (i,f,g,o), dim d = w*HS + (r&7),
  // global gate row = gate*256 + d.
  bf16x8 w0[2][8];    // layer0: [ntile][kstep], K=256
  bf16x8 w1[2][16];   // layer1: K=512 = [Wih1 | Whh1]
  {
    #pragma unroll
    for (int n = 0; n < 2; n++) {
      const int r     = n * 16 + ml;
      const int d     = w * HS + (r & 7);
      const int rglob = (r >> 3) * 256 + d;
      #pragma unroll
      for (int s = 0; s < 8; s++) {
        const float* src = Whh0 + rglob * HH + s * 32 + kq * 8;
        bf16x8 f;
        #pragma unroll
        for (int j = 0; j < 8; j++) f[j] = (__bf16)src[j];
        w0[n][s] = f;
      }
      #pragma unroll
      for (int s = 0; s < 16; s++) {
        const int k = s * 32 + kq * 8;
        const float* src = (k < 256) ? (Wih1 + rglob * HH + k)
                                     : (Whh1 + rglob * HH + (k - 256));
        bf16x8 f;
        #pragma unroll
        for (int j = 0; j < 8; j++) f[j] = (__bf16)src[j];
        w1[n][s] = f;
      }
    }
  }

  // ---- epilogue tables in LDS ----
  if (tid < RS) {
    const int r     = tid;
    const int d     = w * HS + (r & 7);
    const int rglob = (r >> 3) * 256 + d;
    s_b0[r] = bih0[rglob] + bhh0[rglob];
    s_b1[r] = bih1[rglob] + bhh1[rglob];
    #pragma unroll
    for (int j = 0; j < 4; j++) s_wih0[r][j] = Wih0[rglob * 4 + j];
  }

  // ---- zero-init h buffers (2*BB*HH = 32768 elems each, 4 per thread) ----
  {
    const int base = w * 256 + tid;
    #pragma unroll
    for (int j = 0; j < 4; j++) {
      h0buf[base + j * 8192] = (__bf16)0.0f;
      h1buf[base + j * 8192] = (__bf16)0.0f;
    }
  }

  float c0[2] = {0.f, 0.f};
  float c1[2] = {0.f, 0.f};

  // ---- init barrier ----
  __threadfence();
  __syncthreads();
  if (tid == 0)
    __hip_atomic_store(&flags[w], 1, __ATOMIC_RELEASE, __HIP_MEMORY_SCOPE_AGENT);
  if (tid < NWG) {
    while (__hip_atomic_load(&flags[tid], __ATOMIC_RELAXED,
                             __HIP_MEMORY_SCOPE_AGENT) < 1)
      __builtin_amdgcn_s_sleep(1);
  }
  __syncthreads();
  __threadfence();

  const int b_epi = tid >> 2;          // epilogue batch (2 dims per thread)
  const int dl    = (tid & 3) * 2;     // first of 2 hidden dims

  for (int p = 0; p < TT + 2; p++) {
    const int par  = p & 1;       // parity written by L0 this phase
    const int parm = par ^ 1;     // parity of h0(p-1) / h1(p-1)

    const bool doL0 = (p < TT);
    const bool doL1 = (p >= 1 && p <= TT);

    // ---- A-fragments: h0(p-1) and h1(p-2), direct from global ----
    bf16x8 a0[8], a1[8];
    {
      const __bf16* h0p = h0buf + parm * (BB * HH) + (wave * 16 + ml) * HH + kq * 8;
      const __bf16* h1p = h1buf + par  * (BB * HH) + (wave * 16 + ml) * HH + kq * 8;
      #pragma unroll
      for (int s = 0; s < 8; s++) a0[s] = *(const bf16x8*)(h0p + s * 32);
      #pragma unroll
      for (int s = 0; s < 8; s++) a1[s] = *(const bf16x8*)(h1p + s * 32);
    }

    f32x4 acc00 = {0.f,0.f,0.f,0.f}, acc01 = {0.f,0.f,0.f,0.f};
    f32x4 acc10 = {0.f,0.f,0.f,0.f}, acc11 = {0.f,0.f,0.f,0.f};

    if (doL0) {
      #pragma unroll
      for (int s = 0; s < 8; s++) {
        acc00 = __builtin_amdgcn_mfma_f32_16x16x32_bf16(a0[s], w0[0][s], acc00, 0, 0, 0);
        acc01 = __builtin_amdgcn_mfma_f32_16x16x32_bf16(a0[s], w0[1][s], acc01, 0, 0, 0);
      }
    }
    if (doL1) {
      #pragma unroll
      for (int s = 0; s < 8; s++) {
        acc10 = __builtin_amdgcn_mfma_f32_16x16x32_bf16(a0[s], w1[0][s], acc10, 0, 0, 0);
        acc11 = __builtin_amdgcn_mfma_f32_16x16x32_bf16(a0[s], w1[1][s], acc11, 0, 0, 0);
      }
      #pragma unroll
      for (int s = 0; s < 8; s++) {
        acc10 = __builtin_amdgcn_mfma_f32_16x16x32_bf16(a1[s], w1[0][s + 8], acc10, 0, 0, 0);
        acc11 = __builtin_amdgcn_mfma_f32_16x16x32_bf16(a1[s], w1[1][s + 8], acc11, 0, 0, 0);
      }
    }

    // ---- spill gates to LDS (C layout: row=batch=kq*4+j, col=gate-row=ml) ----
    {
      const int bb = wave * 16 + kq * 4;
      if (doL0) {
        #pragma unroll
        for (int j = 0; j < 4; j++) lds_g0[ml     ][bb + j] = acc00[j];
        #pragma unroll
        for (int j = 0; j < 4; j++) lds_g0[16 + ml][bb + j] = acc01[j];
      }
      if (doL1) {
        #pragma unroll
        for (int j = 0; j < 4; j++) lds_g1[ml     ][bb + j] = acc10[j];
        #pragma unroll
        for (int j = 0; j < 4; j++) lds_g1[16 + ml][bb + j] = acc11[j];
      }
    }
    __syncthreads();

    // ---- L0 epilogue: gates -> (c0,h0), publish h0(p) ----
    if (doL0) {
      float x[4];
      #pragma unroll
      for (int j = 0; j < 4; j++) {
        const int ti = p - 3 + j;
        x[j] = (ti >= 0) ? y[b_epi * TT + ti] : -100.0f;
      }
      #pragma unroll
      for (int e = 0; e < 2; e++) {
        const int d = dl + e;
        const float gi = lds_g0[d     ][b_epi] + s_b0[d     ]
          + s_wih0[d     ][0]*x[0] + s_wih0[d     ][1]*x[1] + s_wih0[d     ][2]*x[2] + s_wih0[d     ][3]*x[3];
        const float gf = lds_g0[8 + d ][b_epi] + s_b0[8 + d ]
          + s_wih0[8 + d ][0]*x[0] + s_wih0[8 + d ][1]*x[1] + s_wih0[8 + d ][2]*x[2] + s_wih0[8 + d ][3]*x[3];
        const float gg = lds_g0[16 + d][b_epi] + s_b0[16 + d]
          + s_wih0[16 + d][0]*x[0] + s_wih0[16 + d][1]*x[1] + s_wih0[16 + d][2]*x[2] + s_wih0[16 + d][3]*x[3];
        const float go = lds_g0[24 + d][b_epi] + s_b0[24 + d]
          + s_wih0[24 + d][0]*x[0] + s_wih0[24 + d][1]*x[1] + s_wih0[24 + d][2]*x[2] + s_wih0[24 + d][3]*x[3];
        const float cn = sigf(gf) * c0[e] + sigf(gi) * tanh_f(gg);
        c0[e] = cn;
        const float hn = sigf(go) * tanh_f(cn);
        h0buf[par * (BB * HH) + b_epi * HH + w * HS + d] = (__bf16)hn;
      }
    }

    // ---- L1 epilogue: publish h1(p-1) ----
    if (doL1) {
      #pragma unroll
      for (int e = 0; e < 2; e++) {
        const int d = dl + e;
        const float gi = lds_g1[d     ][b_epi] + s_b1[d     ];
        const float gf = lds_g1[8 + d ][b_epi] + s_b1[8 + d ];
        const float gg = lds_g1[16 + d][b_epi] + s_b1[16 + d];
        const float go = lds_g1[24 + d][b_epi] + s_b1[24 + d];
        const float cn = sigf(gf) * c1[e] + sigf(gi) * tanh_f(gg);
        c1[e] = cn;
        const float hn = sigf(go) * tanh_f(cn);
        h1buf[parm * (BB * HH) + b_epi * HH + w * HS + d] = (__bf16)hn;
      }
    }

    // ---- FC output for step p-2: this WG owns batches 2w, 2w+1 ----
    if (p >= 2) {
      const int t = p - 2;
      const int b = 2 * w + (wave & 1);
      const int c = wave >> 1;
      const __bf16* h1r = h1buf + par * (BB * HH) + b * HH;  // h1(p-2), parity (p-2)&1 == par
      float s = 0.f;
      #pragma unroll
      for (int j = 0; j < 4; j++)
        s += (float)h1r[lane * 4 + j] * Wfc[c * HH + lane * 4 + j];
      #pragma unroll
      for (int off = 32; off > 0; off >>= 1) s += __shfl_down(s, off, 64);
      if (lane == 0) out[b * (TT * 2) + t * 2 + c] = s + bfc[c];
    }

    // ---- inter-WG barrier (release stores, stamped flags, acquire) ----
    __threadfence();
    __syncthreads();
    if (tid == 0)
      __hip_atomic_store(&flags[w], p + 2, __ATOMIC_RELEASE, __HIP_MEMORY_SCOPE_AGENT);
    if (tid < NWG) {
      while (__hip_atomic_load(&flags[tid], __ATOMIC_RELAXED,
                               __HIP_MEMORY_SCOPE_AGENT) < p + 2)
        __builtin_amdgcn_s_sleep(1);
    }
    __syncthreads();
    __threadfence();
  }
}

extern "C" void kernel_launch(void* const* d_in, const int* in_sizes, int n_in,
                              void* d_out, int out_size, void* d_ws, size_t ws_size,
                              hipStream_t stream) {
  char* ws = (char*)d_ws;
  __bf16* h0buf = (__bf16*)(ws);
  __bf16* h1buf = (__bf16*)(ws + 2 * BB * HH * sizeof(__bf16));   // +64 KiB
  int*    flags = (int*)  (ws + 4 * BB * HH * sizeof(__bf16));    // +128 KiB

  lstm2_persistent<<<dim3(NWG), dim3(256), 0, stream>>>(
      (const float*)d_in[0],  (const float*)d_in[1], (const float*)d_in[2],
      (const float*)d_in[3],  (const float*)d_in[4], (const float*)d_in[5],
      (const float*)d_in[6],  (const float*)d_in[7], (const float*)d_in[8],
      (const float*)d_in[9],  (const float*)d_in[10],
      (float*)d_out, h0buf, h1buf, flags);
}

// Round 2
// 14444.376 us; speedup vs baseline: 1.2573x; 1.2573x over previous
//
#include <hip/hip_runtime.h>

// 2-layer LSTM (B=64, T=2048, H=256) as a single persistent cooperative kernel.
// 32 WGs x 256 threads; WG w owns hidden dims [8w, 8w+8) of BOTH layers.
// Recurrent weights live in VGPRs as bf16 MFMA fragments (loaded once).
// Pipeline: phase p computes L0 step p, L1 step p-1, FC output step p-2.
// R2 change: all cross-WG state (h buffers, flags) uses AGENT-scope relaxed
// atomics (global_* sc1 -> Infinity-Cache-coherent, bypasses per-XCD L2) so
// NO buffer_wbl2/buffer_inv on the critical path; hard spin instead of s_sleep.

#define NWG 32
#define BB 64
#define TT 2048
#define HH 256
#define HS 8    // hidden dims per WG per layer
#define RS 32   // gate rows per WG per layer (4*HS)

typedef float  f32x4  __attribute__((ext_vector_type(4)));
typedef __bf16 bf16x8 __attribute__((ext_vector_type(8)));
typedef unsigned long long u64;
typedef unsigned int u32;

__device__ __forceinline__ float sigf(float x)   { return 1.0f / (1.0f + __expf(-x)); }
__device__ __forceinline__ float tanh_f(float x) { return 2.0f / (1.0f + __expf(-2.0f * x)) - 1.0f; }

__device__ __forceinline__ bf16x8 ld_frag_llc(const __bf16* p) {
  const u64* q = (const u64*)p;
  u64 lo = __hip_atomic_load(q,     __ATOMIC_RELAXED, __HIP_MEMORY_SCOPE_AGENT);
  u64 hi = __hip_atomic_load(q + 1, __ATOMIC_RELAXED, __HIP_MEMORY_SCOPE_AGENT);
  union { u64 u[2]; bf16x8 v; } cvt;
  cvt.u[0] = lo; cvt.u[1] = hi;
  return cvt.v;
}

__device__ __forceinline__ void st_pair_llc(__bf16* p, float a, float b) {
  union { __bf16 h[2]; u32 u; } pk;
  pk.h[0] = (__bf16)a; pk.h[1] = (__bf16)b;
  __hip_atomic_store((u32*)p, pk.u, __ATOMIC_RELAXED, __HIP_MEMORY_SCOPE_AGENT);
}

__global__ __launch_bounds__(256, 1) void lstm2_persistent(
    const float* __restrict__ y,
    const float* __restrict__ Wih0, const float* __restrict__ Whh0,
    const float* __restrict__ bih0, const float* __restrict__ bhh0,
    const float* __restrict__ Wih1, const float* __restrict__ Whh1,
    const float* __restrict__ bih1, const float* __restrict__ bhh1,
    const float* __restrict__ Wfc,  const float* __restrict__ bfc,
    float* __restrict__ out,
    __bf16* __restrict__ h0buf,   // [2][BB][HH] bf16, parity-double-buffered
    __bf16* __restrict__ h1buf,   // [2][BB][HH] bf16
    int* __restrict__ flags)      // [NWG] step stamps (poison 0xAA.. < 0 is safe)
{
  const int w    = blockIdx.x;
  const int tid  = threadIdx.x;
  const int wave = tid >> 6;
  const int lane = tid & 63;
  const int ml   = lane & 15;   // row-within-tile for A, col (gate row) for B
  const int kq   = lane >> 4;   // k-quad

  __shared__ float lds_g0[RS][BB + 4];
  __shared__ float lds_g1[RS][BB + 4];
  __shared__ float s_wih0[RS][4];
  __shared__ float s_b0[RS];
  __shared__ float s_b1[RS];

  // ---- load recurrent weights into per-wave VGPR B-fragments (bf16) ----
  bf16x8 w0[2][8];    // layer0: [ntile][kstep], K=256
  bf16x8 w1[2][16];   // layer1: K=512 = [Wih1 | Whh1]
  {
    #pragma unroll
    for (int n = 0; n < 2; n++) {
      const int r     = n * 16 + ml;
      const int d     = w * HS + (r & 7);
      const int rglob = (r >> 3) * 256 + d;
      #pragma unroll
      for (int s = 0; s < 8; s++) {
        const float* src = Whh0 + rglob * HH + s * 32 + kq * 8;
        bf16x8 f;
        #pragma unroll
        for (int j = 0; j < 8; j++) f[j] = (__bf16)src[j];
        w0[n][s] = f;
      }
      #pragma unroll
      for (int s = 0; s < 16; s++) {
        const int k = s * 32 + kq * 8;
        const float* src = (k < 256) ? (Wih1 + rglob * HH + k)
                                     : (Whh1 + rglob * HH + (k - 256));
        bf16x8 f;
        #pragma unroll
        for (int j = 0; j < 8; j++) f[j] = (__bf16)src[j];
        w1[n][s] = f;
      }
    }
  }

  // ---- epilogue tables in LDS ----
  if (tid < RS) {
    const int r     = tid;
    const int d     = w * HS + (r & 7);
    const int rglob = (r >> 3) * 256 + d;
    s_b0[r] = bih0[rglob] + bhh0[rglob];
    s_b1[r] = bih1[rglob] + bhh1[rglob];
    #pragma unroll
    for (int j = 0; j < 4; j++) s_wih0[r][j] = Wih0[rglob * 4 + j];
  }

  // ---- zero-init h buffers via LLC-coherent stores ----
  {
    u32* H0 = (u32*)h0buf;   // 16384 dwords
    u32* H1 = (u32*)h1buf;
    const int base = w * 256 + tid;
    #pragma unroll
    for (int j = 0; j < 2; j++) {
      __hip_atomic_store(H0 + base + j * 8192, 0u, __ATOMIC_RELAXED, __HIP_MEMORY_SCOPE_AGENT);
      __hip_atomic_store(H1 + base + j * 8192, 0u, __ATOMIC_RELAXED, __HIP_MEMORY_SCOPE_AGENT);
    }
  }

  float c0[2] = {0.f, 0.f};
  float c1[2] = {0.f, 0.f};

  // ---- init barrier: drain stores, stamp, spin ----
  asm volatile("s_waitcnt vmcnt(0)" ::: "memory");
  __syncthreads();
  if (tid == 0)
    __hip_atomic_store(&flags[w], 1, __ATOMIC_RELAXED, __HIP_MEMORY_SCOPE_AGENT);
  if (tid < NWG) {
    while (__hip_atomic_load(&flags[tid], __ATOMIC_RELAXED,
                             __HIP_MEMORY_SCOPE_AGENT) < 1) {}
  }
  __syncthreads();

  const int b_epi = tid >> 2;          // epilogue batch (2 dims per thread)
  const int dl    = (tid & 3) * 2;     // first of 2 hidden dims

  for (int p = 0; p < TT + 2; p++) {
    const int par  = p & 1;       // parity written by L0 this phase
    const int parm = par ^ 1;     // parity of h0(p-1) / h1(p-1)

    const bool doL0 = (p < TT);
    const bool doL1 = (p >= 1 && p <= TT);

    // ---- A-fragments: h0(p-1) and h1(p-2), LLC-coherent loads ----
    bf16x8 a0[8], a1[8];
    {
      const __bf16* h0p = h0buf + parm * (BB * HH) + (wave * 16 + ml) * HH + kq * 8;
      const __bf16* h1p = h1buf + par  * (BB * HH) + (wave * 16 + ml) * HH + kq * 8;
      #pragma unroll
      for (int s = 0; s < 8; s++) a0[s] = ld_frag_llc(h0p + s * 32);
      #pragma unroll
      for (int s = 0; s < 8; s++) a1[s] = ld_frag_llc(h1p + s * 32);
    }

    f32x4 acc00 = {0.f,0.f,0.f,0.f}, acc01 = {0.f,0.f,0.f,0.f};
    f32x4 acc10 = {0.f,0.f,0.f,0.f}, acc11 = {0.f,0.f,0.f,0.f};

    if (doL0) {
      #pragma unroll
      for (int s = 0; s < 8; s++) {
        acc00 = __builtin_amdgcn_mfma_f32_16x16x32_bf16(a0[s], w0[0][s], acc00, 0, 0, 0);
        acc01 = __builtin_amdgcn_mfma_f32_16x16x32_bf16(a0[s], w0[1][s], acc01, 0, 0, 0);
      }
    }
    if (doL1) {
      #pragma unroll
      for (int s = 0; s < 8; s++) {
        acc10 = __builtin_amdgcn_mfma_f32_16x16x32_bf16(a0[s], w1[0][s], acc10, 0, 0, 0);
        acc11 = __builtin_amdgcn_mfma_f32_16x16x32_bf16(a0[s], w1[1][s], acc11, 0, 0, 0);
      }
      #pragma unroll
      for (int s = 0; s < 8; s++) {
        acc10 = __builtin_amdgcn_mfma_f32_16x16x32_bf16(a1[s], w1[0][s + 8], acc10, 0, 0, 0);
        acc11 = __builtin_amdgcn_mfma_f32_16x16x32_bf16(a1[s], w1[1][s + 8], acc11, 0, 0, 0);
      }
    }

    // ---- spill gates to LDS (C layout: row=batch=kq*4+j, col=gate-row=ml) ----
    {
      const int bb = wave * 16 + kq * 4;
      if (doL0) {
        #pragma unroll
        for (int j = 0; j < 4; j++) lds_g0[ml     ][bb + j] = acc00[j];
        #pragma unroll
        for (int j = 0; j < 4; j++) lds_g0[16 + ml][bb + j] = acc01[j];
      }
      if (doL1) {
        #pragma unroll
        for (int j = 0; j < 4; j++) lds_g1[ml     ][bb + j] = acc10[j];
        #pragma unroll
        for (int j = 0; j < 4; j++) lds_g1[16 + ml][bb + j] = acc11[j];
      }
    }
    __syncthreads();

    // ---- L0 epilogue: gates -> (c0,h0), publish h0(p) ----
    if (doL0) {
      float x[4];
      #pragma unroll
      for (int j = 0; j < 4; j++) {
        const int ti = p - 3 + j;
        x[j] = (ti >= 0) ? y[b_epi * TT + ti] : -100.0f;
      }
      float hn[2];
      #pragma unroll
      for (int e = 0; e < 2; e++) {
        const int d = dl + e;
        const float gi = lds_g0[d     ][b_epi] + s_b0[d     ]
          + s_wih0[d     ][0]*x[0] + s_wih0[d     ][1]*x[1] + s_wih0[d     ][2]*x[2] + s_wih0[d     ][3]*x[3];
        const float gf = lds_g0[8 + d ][b_epi] + s_b0[8 + d ]
          + s_wih0[8 + d ][0]*x[0] + s_wih0[8 + d ][1]*x[1] + s_wih0[8 + d ][2]*x[2] + s_wih0[8 + d ][3]*x[3];
        const float gg = lds_g0[16 + d][b_epi] + s_b0[16 + d]
          + s_wih0[16 + d][0]*x[0] + s_wih0[16 + d][1]*x[1] + s_wih0[16 + d][2]*x[2] + s_wih0[16 + d][3]*x[3];
        const float go = lds_g0[24 + d][b_epi] + s_b0[24 + d]
          + s_wih0[24 + d][0]*x[0] + s_wih0[24 + d][1]*x[1] + s_wih0[24 + d][2]*x[2] + s_wih0[24 + d][3]*x[3];
        const float cn = sigf(gf) * c0[e] + sigf(gi) * tanh_f(gg);
        c0[e] = cn;
        hn[e] = sigf(go) * tanh_f(cn);
      }
      st_pair_llc(h0buf + par * (BB * HH) + b_epi * HH + w * HS + dl, hn[0], hn[1]);
    }

    // ---- L1 epilogue: publish h1(p-1) ----
    if (doL1) {
      float hn[2];
      #pragma unroll
      for (int e = 0; e < 2; e++) {
        const int d = dl + e;
        const float gi = lds_g1[d     ][b_epi] + s_b1[d     ];
        const float gf = lds_g1[8 + d ][b_epi] + s_b1[8 + d ];
        const float gg = lds_g1[16 + d][b_epi] + s_b1[16 + d];
        const float go = lds_g1[24 + d][b_epi] + s_b1[24 + d];
        const float cn = sigf(gf) * c1[e] + sigf(gi) * tanh_f(gg);
        c1[e] = cn;
        hn[e] = sigf(go) * tanh_f(cn);
      }
      st_pair_llc(h1buf + parm * (BB * HH) + b_epi * HH + w * HS + dl, hn[0], hn[1]);
    }

    // ---- FC output for step p-2: this WG owns batches 2w, 2w+1 ----
    if (p >= 2) {
      const int t = p - 2;
      const int b = 2 * w + (wave & 1);
      const int c = wave >> 1;
      const __bf16* h1r = h1buf + par * (BB * HH) + b * HH;  // h1(p-2)
      u64 qv = __hip_atomic_load((const u64*)h1r + lane,
                                 __ATOMIC_RELAXED, __HIP_MEMORY_SCOPE_AGENT);
      union { u64 u; __bf16 h[4]; } c4; c4.u = qv;
      float s = 0.f;
      #pragma unroll
      for (int j = 0; j < 4; j++)
        s += (float)c4.h[j] * Wfc[c * HH + lane * 4 + j];
      #pragma unroll
      for (int off = 32; off > 0; off >>= 1) s += __shfl_down(s, off, 64);
      if (lane == 0) out[b * (TT * 2) + t * 2 + c] = s + bfc[c];
    }

    // ---- inter-WG barrier: drain sc1 stores, stamp, hard spin ----
    asm volatile("s_waitcnt vmcnt(0)" ::: "memory");
    __syncthreads();
    if (tid == 0)
      __hip_atomic_store(&flags[w], p + 2, __ATOMIC_RELAXED, __HIP_MEMORY_SCOPE_AGENT);
    if (tid < NWG) {
      while (__hip_atomic_load(&flags[tid], __ATOMIC_RELAXED,
                               __HIP_MEMORY_SCOPE_AGENT) < p + 2) {}
    }
    __syncthreads();
  }
}

extern "C" void kernel_launch(void* const* d_in, const int* in_sizes, int n_in,
                              void* d_out, int out_size, void* d_ws, size_t ws_size,
                              hipStream_t stream) {
  char* ws = (char*)d_ws;
  __bf16* h0buf = (__bf16*)(ws);
  __bf16* h1buf = (__bf16*)(ws + 2 * BB * HH * sizeof(__bf16));   // +64 KiB
  int*    flags = (int*)  (ws + 4 * BB * HH * sizeof(__bf16));    // +128 KiB

  lstm2_persistent<<<dim3(NWG), dim3(256), 0, stream>>>(
      (const float*)d_in[0],  (const float*)d_in[1], (const float*)d_in[2],
      (const float*)d_in[3],  (const float*)d_in[4], (const float*)d_in[5],
      (const float*)d_in[6],  (const float*)d_in[7], (const float*)d_in[8],
      (const float*)d_in[9],  (const float*)d_in[10],
      (float*)d_out, h0buf, h1buf, flags);
}

// Round 3
// 9303.645 us; speedup vs baseline: 1.9521x; 1.5526x over previous
//
#include <hip/hip_runtime.h>

// 2-layer LSTM (B=64, T=2048, H=256) as a single persistent cooperative kernel.
// 32 WGs x 256 threads; WG w owns hidden dims [8w, 8w+8) of BOTH layers.
// Recurrent weights live in VGPRs as bf16 MFMA fragments (loaded once).
// Pipeline: phase p computes L0 step p, L1 step p-1, FC output step p-2.
// R3 changes vs R2:
//  - h buffers re-laid-out as [parity][wg][batch][8 dims] so each WG's
//    per-phase publish is one coalesced line-aligned 1 KB block (kills the
//    partial-sector RMW HBM traffic seen in R2: 260KB fetch/phase).
//  - FC/out computation moved AFTER the flag store (overlaps barrier).
//  - y (input) loads hoisted above the MFMA block.

#define NWG 32
#define BB 64
#define TT 2048
#define HH 256
#define HS 8    // hidden dims per WG per layer
#define RS 32   // gate rows per WG per layer (4*HS)

typedef float  f32x4  __attribute__((ext_vector_type(4)));
typedef __bf16 bf16x8 __attribute__((ext_vector_type(8)));
typedef unsigned long long u64;
typedef unsigned int u32;

__device__ __forceinline__ float sigf(float x)   { return 1.0f / (1.0f + __expf(-x)); }
__device__ __forceinline__ float tanh_f(float x) { return 2.0f / (1.0f + __expf(-2.0f * x)) - 1.0f; }

// LLC-coherent (agent-scope) 16B fragment load from strip layout.
__device__ __forceinline__ bf16x8 ld_frag_llc(const __bf16* p) {
  const u64* q = (const u64*)p;
  u64 lo = __hip_atomic_load(q,     __ATOMIC_RELAXED, __HIP_MEMORY_SCOPE_AGENT);
  u64 hi = __hip_atomic_load(q + 1, __ATOMIC_RELAXED, __HIP_MEMORY_SCOPE_AGENT);
  union { u64 u[2]; bf16x8 v; } cvt;
  cvt.u[0] = lo; cvt.u[1] = hi;
  return cvt.v;
}

__device__ __forceinline__ void st_pair_llc(__bf16* p, float a, float b) {
  union { __bf16 h[2]; u32 u; } pk;
  pk.h[0] = (__bf16)a; pk.h[1] = (__bf16)b;
  __hip_atomic_store((u32*)p, pk.u, __ATOMIC_RELAXED, __HIP_MEMORY_SCOPE_AGENT);
}

__global__ __launch_bounds__(256, 1) void lstm2_persistent(
    const float* __restrict__ y,
    const float* __restrict__ Wih0, const float* __restrict__ Whh0,
    const float* __restrict__ bih0, const float* __restrict__ bhh0,
    const float* __restrict__ Wih1, const float* __restrict__ Whh1,
    const float* __restrict__ bih1, const float* __restrict__ bhh1,
    const float* __restrict__ Wfc,  const float* __restrict__ bfc,
    float* __restrict__ out,
    __bf16* __restrict__ h0buf,   // [2][NWG][BB][HS] bf16 strip layout
    __bf16* __restrict__ h1buf,   // [2][NWG][BB][HS] bf16 strip layout
    int* __restrict__ flags)      // [NWG] step stamps
{
  const int w    = blockIdx.x;
  const int tid  = threadIdx.x;
  const int wave = tid >> 6;
  const int lane = tid & 63;
  const int ml   = lane & 15;   // row-within-tile for A, col (gate row) for B
  const int kq   = lane >> 4;   // k-quad

  __shared__ float lds_g0[RS][BB + 4];
  __shared__ float lds_g1[RS][BB + 4];
  __shared__ float s_wih0[RS][4];
  __shared__ float s_b0[RS];
  __shared__ float s_b1[RS];

  // ---- load recurrent weights into per-wave VGPR B-fragments (bf16) ----
  bf16x8 w0[2][8];    // layer0: [ntile][kstep], K=256
  bf16x8 w1[2][16];   // layer1: K=512 = [Wih1 | Whh1]
  {
    #pragma unroll
    for (int n = 0; n < 2; n++) {
      const int r     = n * 16 + ml;
      const int d     = w * HS + (r & 7);
      const int rglob = (r >> 3) * 256 + d;
      #pragma unroll
      for (int s = 0; s < 8; s++) {
        const float* src = Whh0 + rglob * HH + s * 32 + kq * 8;
        bf16x8 f;
        #pragma unroll
        for (int j = 0; j < 8; j++) f[j] = (__bf16)src[j];
        w0[n][s] = f;
      }
      #pragma unroll
      for (int s = 0; s < 16; s++) {
        const int k = s * 32 + kq * 8;
        const float* src = (k < 256) ? (Wih1 + rglob * HH + k)
                                     : (Whh1 + rglob * HH + (k - 256));
        bf16x8 f;
        #pragma unroll
        for (int j = 0; j < 8; j++) f[j] = (__bf16)src[j];
        w1[n][s] = f;
      }
    }
  }

  // ---- epilogue tables in LDS ----
  if (tid < RS) {
    const int r     = tid;
    const int d     = w * HS + (r & 7);
    const int rglob = (r >> 3) * 256 + d;
    s_b0[r] = bih0[rglob] + bhh0[rglob];
    s_b1[r] = bih1[rglob] + bhh1[rglob];
    #pragma unroll
    for (int j = 0; j < 4; j++) s_wih0[r][j] = Wih0[rglob * 4 + j];
  }

  // ---- zero-init h buffers via LLC-coherent stores ----
  {
    u32* H0 = (u32*)h0buf;   // 16384 dwords each
    u32* H1 = (u32*)h1buf;
    const int base = w * 256 + tid;
    #pragma unroll
    for (int j = 0; j < 2; j++) {
      __hip_atomic_store(H0 + base + j * 8192, 0u, __ATOMIC_RELAXED, __HIP_MEMORY_SCOPE_AGENT);
      __hip_atomic_store(H1 + base + j * 8192, 0u, __ATOMIC_RELAXED, __HIP_MEMORY_SCOPE_AGENT);
    }
  }

  float c0[2] = {0.f, 0.f};
  float c1[2] = {0.f, 0.f};

  // ---- init barrier: drain stores, stamp, spin ----
  asm volatile("s_waitcnt vmcnt(0)" ::: "memory");
  __syncthreads();
  if (tid == 0)
    __hip_atomic_store(&flags[w], 1, __ATOMIC_RELAXED, __HIP_MEMORY_SCOPE_AGENT);
  if (tid < NWG) {
    while (__hip_atomic_load(&flags[tid], __ATOMIC_RELAXED,
                             __HIP_MEMORY_SCOPE_AGENT) < 1) {}
  }
  __syncthreads();

  const int b_epi = tid >> 2;          // epilogue batch (2 dims per thread)
  const int dl    = (tid & 3) * 2;     // first of 2 hidden dims

  for (int p = 0; p < TT + 2; p++) {
    const int par  = p & 1;       // parity written by L0 this phase
    const int parm = par ^ 1;     // parity of h0(p-1) / h1(p-1)

    const bool doL0 = (p < TT);
    const bool doL1 = (p >= 1 && p <= TT);

    // ---- A-fragments: h0(p-1) and h1(p-2), strip layout ----
    // frag s, lane(ml,kq): k = s*32+kq*8 -> strip wg = s*4+kq, row = wave*16+ml
    bf16x8 a0[8], a1[8];
    {
      const int row = wave * 16 + ml;
      const __bf16* h0p = h0buf + (parm * NWG * BB + kq * BB + row) * HS;
      const __bf16* h1p = h1buf + (par  * NWG * BB + kq * BB + row) * HS;
      #pragma unroll
      for (int s = 0; s < 8; s++) a0[s] = ld_frag_llc(h0p + s * 4 * BB * HS);
      #pragma unroll
      for (int s = 0; s < 8; s++) a1[s] = ld_frag_llc(h1p + s * 4 * BB * HS);
    }

    // ---- hoisted input loads (hide L2 latency under MFMA) ----
    float x[4];
    #pragma unroll
    for (int j = 0; j < 4; j++) {
      const int ti = p - 3 + j;
      x[j] = (ti >= 0 && doL0) ? y[b_epi * TT + ti] : -100.0f;
    }

    f32x4 acc00 = {0.f,0.f,0.f,0.f}, acc01 = {0.f,0.f,0.f,0.f};
    f32x4 acc10 = {0.f,0.f,0.f,0.f}, acc11 = {0.f,0.f,0.f,0.f};

    if (doL0) {
      #pragma unroll
      for (int s = 0; s < 8; s++) {
        acc00 = __builtin_amdgcn_mfma_f32_16x16x32_bf16(a0[s], w0[0][s], acc00, 0, 0, 0);
        acc01 = __builtin_amdgcn_mfma_f32_16x16x32_bf16(a0[s], w0[1][s], acc01, 0, 0, 0);
      }
    }
    if (doL1) {
      #pragma unroll
      for (int s = 0; s < 8; s++) {
        acc10 = __builtin_amdgcn_mfma_f32_16x16x32_bf16(a0[s], w1[0][s], acc10, 0, 0, 0);
        acc11 = __builtin_amdgcn_mfma_f32_16x16x32_bf16(a0[s], w1[1][s], acc11, 0, 0, 0);
      }
      #pragma unroll
      for (int s = 0; s < 8; s++) {
        acc10 = __builtin_amdgcn_mfma_f32_16x16x32_bf16(a1[s], w1[0][s + 8], acc10, 0, 0, 0);
        acc11 = __builtin_amdgcn_mfma_f32_16x16x32_bf16(a1[s], w1[1][s + 8], acc11, 0, 0, 0);
      }
    }

    // ---- spill gates to LDS (C layout: row=batch=kq*4+j, col=gate-row=ml) ----
    {
      const int bb = wave * 16 + kq * 4;
      if (doL0) {
        #pragma unroll
        for (int j = 0; j < 4; j++) lds_g0[ml     ][bb + j] = acc00[j];
        #pragma unroll
        for (int j = 0; j < 4; j++) lds_g0[16 + ml][bb + j] = acc01[j];
      }
      if (doL1) {
        #pragma unroll
        for (int j = 0; j < 4; j++) lds_g1[ml     ][bb + j] = acc10[j];
        #pragma unroll
        for (int j = 0; j < 4; j++) lds_g1[16 + ml][bb + j] = acc11[j];
      }
    }
    __syncthreads();

    // ---- L0 epilogue: gates -> (c0,h0), publish h0(p) (coalesced strip) ----
    if (doL0) {
      float hn[2];
      #pragma unroll
      for (int e = 0; e < 2; e++) {
        const int d = dl + e;
        const float gi = lds_g0[d     ][b_epi] + s_b0[d     ]
          + s_wih0[d     ][0]*x[0] + s_wih0[d     ][1]*x[1] + s_wih0[d     ][2]*x[2] + s_wih0[d     ][3]*x[3];
        const float gf = lds_g0[8 + d ][b_epi] + s_b0[8 + d ]
          + s_wih0[8 + d ][0]*x[0] + s_wih0[8 + d ][1]*x[1] + s_wih0[8 + d ][2]*x[2] + s_wih0[8 + d ][3]*x[3];
        const float gg = lds_g0[16 + d][b_epi] + s_b0[16 + d]
          + s_wih0[16 + d][0]*x[0] + s_wih0[16 + d][1]*x[1] + s_wih0[16 + d][2]*x[2] + s_wih0[16 + d][3]*x[3];
        const float go = lds_g0[24 + d][b_epi] + s_b0[24 + d]
          + s_wih0[24 + d][0]*x[0] + s_wih0[24 + d][1]*x[1] + s_wih0[24 + d][2]*x[2] + s_wih0[24 + d][3]*x[3];
        const float cn = sigf(gf) * c0[e] + sigf(gi) * tanh_f(gg);
        c0[e] = cn;
        hn[e] = sigf(go) * tanh_f(cn);
      }
      st_pair_llc(h0buf + (par * NWG * BB + w * BB + b_epi) * HS + dl, hn[0], hn[1]);
    }

    // ---- L1 epilogue: publish h1(p-1) (coalesced strip) ----
    if (doL1) {
      float hn[2];
      #pragma unroll
      for (int e = 0; e < 2; e++) {
        const int d = dl + e;
        const float gi = lds_g1[d     ][b_epi] + s_b1[d     ];
        const float gf = lds_g1[8 + d ][b_epi] + s_b1[8 + d ];
        const float gg = lds_g1[16 + d][b_epi] + s_b1[16 + d];
        const float go = lds_g1[24 + d][b_epi] + s_b1[24 + d];
        const float cn = sigf(gf) * c1[e] + sigf(gi) * tanh_f(gg);
        c1[e] = cn;
        hn[e] = sigf(go) * tanh_f(cn);
      }
      st_pair_llc(h1buf + (parm * NWG * BB + w * BB + b_epi) * HS + dl, hn[0], hn[1]);
    }

    // ---- barrier publish: drain h stores, stamp flag ----
    asm volatile("s_waitcnt vmcnt(0)" ::: "memory");
    __syncthreads();
    if (tid == 0)
      __hip_atomic_store(&flags[w], p + 2, __ATOMIC_RELAXED, __HIP_MEMORY_SCOPE_AGENT);

    // ---- FC output for step p-2 (overlaps barrier propagation):
    // reads h1(p-2) = parity par, published 2 phases ago. WG w owns b=2w,2w+1.
    if (p >= 2) {
      const int t = p - 2;
      const int b = 2 * w + (wave & 1);
      const int c = wave >> 1;
      // dims d = lane*4 .. lane*4+3 -> strip wg = lane>>1, offset (lane&1)*4
      const __bf16* h1r = h1buf + (par * NWG * BB + (lane >> 1) * BB + b) * HS + (lane & 1) * 4;
      u64 qv = __hip_atomic_load((const u64*)h1r,
                                 __ATOMIC_RELAXED, __HIP_MEMORY_SCOPE_AGENT);
      union { u64 u; __bf16 h[4]; } c4; c4.u = qv;
      float s = 0.f;
      #pragma unroll
      for (int j = 0; j < 4; j++)
        s += (float)c4.h[j] * Wfc[c * HH + lane * 4 + j];
      #pragma unroll
      for (int off = 32; off > 0; off >>= 1) s += __shfl_down(s, off, 64);
      if (lane == 0) out[b * (TT * 2) + t * 2 + c] = s + bfc[c];
    }

    // ---- barrier wait ----
    if (tid < NWG) {
      while (__hip_atomic_load(&flags[tid], __ATOMIC_RELAXED,
                               __HIP_MEMORY_SCOPE_AGENT) < p + 2) {}
    }
    __syncthreads();
  }
}

extern "C" void kernel_launch(void* const* d_in, const int* in_sizes, int n_in,
                              void* d_out, int out_size, void* d_ws, size_t ws_size,
                              hipStream_t stream) {
  char* ws = (char*)d_ws;
  __bf16* h0buf = (__bf16*)(ws);
  __bf16* h1buf = (__bf16*)(ws + 2 * NWG * BB * HS * sizeof(__bf16));   // +64 KiB
  int*    flags = (int*)  (ws + 4 * NWG * BB * HS * sizeof(__bf16));    // +128 KiB

  lstm2_persistent<<<dim3(NWG), dim3(256), 0, stream>>>(
      (const float*)d_in[0],  (const float*)d_in[1], (const float*)d_in[2],
      (const float*)d_in[3],  (const float*)d_in[4], (const float*)d_in[5],
      (const float*)d_in[6],  (const float*)d_in[7], (const float*)d_in[8],
      (const float*)d_in[9],  (const float*)d_in[10],
      (float*)d_out, h0buf, h1buf, flags);
}

// Round 5
// 7368.884 us; speedup vs baseline: 2.4646x; 1.2626x over previous
//
#include <hip/hip_runtime.h>

// 2-layer LSTM (B=64, T=2048, H=256), persistent kernel, SINGLE-XCD edition.
// R5 = R4 with the deadlock fixed: R4's consumer poll
// (__hip_atomic_fetch_add(p,0,WORKGROUP)) was legally optimized by LLVM into a
// workgroup-scope atomic LOAD -> plain global_load_dword -> stale L1 hit
// forever -> hang. R5 polls via inline-asm `global_atomic_or ... sc0`
// (real RMW, executes at the XCD-local TCC, returns old value) which cannot
// be optimized and never reads L1.
// Everything else as R4:
//  - 32 WGs elected onto ONE XCD via HW_REG_XCC_ID + device-scope registration
//  - h publishes: plain write-through stores -> local L2
//  - h reads: plain loads after per-phase `buffer_inv sc0` (L1 invalidate)
//  - flags: plain store (producer), asm atomic-or-0 sc0 (consumer)

#define NWG 32
#define BB 64
#define TT 2048
#define HH 256
#define HS 8    // hidden dims per WG per layer
#define RS 32   // gate rows per WG per layer (4*HS)

// workspace layout (dwords)
#define WS_H0    0        // 16384 dwords (65536 B)
#define WS_H1    16384    // 16384 dwords
#define WS_FLAGS 32768    // 32 flags, stride 16 dwords (512 dwords)
#define WS_CNT   33280    // 16 dwords
#define WS_WIN   33296    // 1 dword
#define WS_NZERO 33296    // zeroed [0, WS_NZERO); winner set separately

typedef float  f32x4  __attribute__((ext_vector_type(4)));
typedef __bf16 bf16x8 __attribute__((ext_vector_type(8)));
typedef unsigned long long u64;
typedef unsigned int u32;

__device__ __forceinline__ float sigf(float x)   { return 1.0f / (1.0f + __expf(-x)); }
__device__ __forceinline__ float tanh_f(float x) { return 2.0f / (1.0f + __expf(-2.0f * x)) - 1.0f; }

// Atomic-or-0 with return, forced at the local TCC (L2). sc0 = return old.
__device__ __forceinline__ int poll_or0_sc0(int* p) {
  int old;
  asm volatile("global_atomic_or %0, %1, %2, off sc0\n\t"
               "s_waitcnt vmcnt(0)"
               : "=&v"(old)
               : "v"(p), "v"(0)
               : "memory");
  return old;
}

__global__ void init_ws(u32* ws) {
  int i = blockIdx.x * blockDim.x + threadIdx.x;
  for (; i < WS_NZERO; i += gridDim.x * blockDim.x) ws[i] = 0u;
  if (blockIdx.x == 0 && threadIdx.x == 0) ((int*)ws)[WS_WIN] = -1;
}

__global__ __launch_bounds__(256, 1) void lstm2_persistent(
    const float* __restrict__ y,
    const float* __restrict__ Wih0, const float* __restrict__ Whh0,
    const float* __restrict__ bih0, const float* __restrict__ bhh0,
    const float* __restrict__ Wih1, const float* __restrict__ Whh1,
    const float* __restrict__ bih1, const float* __restrict__ bhh1,
    const float* __restrict__ Wfc,  const float* __restrict__ bfc,
    float* __restrict__ out,
    u32* __restrict__ ws)
{
  __bf16* h0buf = (__bf16*)(ws + WS_H0);   // [2][NWG][BB][HS]
  __bf16* h1buf = (__bf16*)(ws + WS_H1);   // [2][NWG][BB][HS]
  int*    flags = (int*)(ws + WS_FLAGS);   // stride 16 dwords per WG
  int*    cnt   = (int*)(ws + WS_CNT);
  int*    winner= (int*)(ws + WS_WIN);

  const int tid  = threadIdx.x;

  // ---- same-XCD election: 32 WGs on one XCD participate, rest exit ----
  __shared__ int s_w;
  if (tid == 0) {
    // HW_REG_XCC_ID = 20, offset 0, size 32 -> imm = 20 | (31<<11)
    int xcc = __builtin_amdgcn_s_getreg(20 | (31 << 11)) & 0xF;
    int r = atomicAdd(&cnt[xcc], 1);               // device-scope (IC), one-time
    if (r == NWG - 1) atomicCAS(winner, -1, xcc);  // 32nd registrant claims
    int wv;
    while ((wv = __hip_atomic_load(winner, __ATOMIC_RELAXED,
                                   __HIP_MEMORY_SCOPE_AGENT)) == -1) {}
    s_w = (wv == xcc && r < NWG) ? r : -1;
  }
  __syncthreads();
  const int w = s_w;
  if (w < 0) return;   // non-participant WG exits, frees its CU

  const int wave = tid >> 6;
  const int lane = tid & 63;
  const int ml   = lane & 15;   // row-within-tile for A, col (gate row) for B
  const int kq   = lane >> 4;   // k-quad

  __shared__ float lds_g0[RS][BB + 4];
  __shared__ float lds_g1[RS][BB + 4];
  __shared__ float s_wih0[RS][4];
  __shared__ float s_b0[RS];
  __shared__ float s_b1[RS];

  // ---- load recurrent weights into per-wave VGPR B-fragments (bf16) ----
  bf16x8 w0[2][8];    // layer0: [ntile][kstep], K=256
  bf16x8 w1[2][16];   // layer1: K=512 = [Wih1 | Whh1]
  {
    #pragma unroll
    for (int n = 0; n < 2; n++) {
      const int r     = n * 16 + ml;
      const int d     = w * HS + (r & 7);
      const int rglob = (r >> 3) * 256 + d;
      #pragma unroll
      for (int s = 0; s < 8; s++) {
        const float* src = Whh0 + rglob * HH + s * 32 + kq * 8;
        bf16x8 f;
        #pragma unroll
        for (int j = 0; j < 8; j++) f[j] = (__bf16)src[j];
        w0[n][s] = f;
      }
      #pragma unroll
      for (int s = 0; s < 16; s++) {
        const int k = s * 32 + kq * 8;
        const float* src = (k < 256) ? (Wih1 + rglob * HH + k)
                                     : (Whh1 + rglob * HH + (k - 256));
        bf16x8 f;
        #pragma unroll
        for (int j = 0; j < 8; j++) f[j] = (__bf16)src[j];
        w1[n][s] = f;
      }
    }
  }

  // ---- epilogue tables in LDS ----
  if (tid < RS) {
    const int r     = tid;
    const int d     = w * HS + (r & 7);
    const int rglob = (r >> 3) * 256 + d;
    s_b0[r] = bih0[rglob] + bhh0[rglob];
    s_b1[r] = bih1[rglob] + bhh1[rglob];
    #pragma unroll
    for (int j = 0; j < 4; j++) s_wih0[r][j] = Wih0[rglob * 4 + j];
  }
  __syncthreads();

  float c0[2] = {0.f, 0.f};
  float c1[2] = {0.f, 0.f};

  const int b_epi = tid >> 2;          // epilogue batch (2 dims per thread)
  const int dl    = (tid & 3) * 2;     // first of 2 hidden dims

  for (int p = 0; p < TT + 2; p++) {
    const int par  = p & 1;       // parity written by L0 this phase
    const int parm = par ^ 1;     // parity of h0(p-1) / h1(p-1)

    const bool doL0 = (p < TT);
    const bool doL1 = (p >= 1 && p <= TT);

    // ---- invalidate vector L1 so plain loads see this phase's L2 data ----
    asm volatile("buffer_inv sc0" ::: "memory");

    // ---- A-fragments: h0(p-1) and h1(p-2), plain L2-served loads ----
    // frag s, lane(ml,kq): k = s*32+kq*8 -> strip wg = s*4+kq, row = wave*16+ml
    bf16x8 a0[8], a1[8];
    {
      const int row = wave * 16 + ml;
      const __bf16* h0p = h0buf + (parm * NWG * BB + kq * BB + row) * HS;
      const __bf16* h1p = h1buf + (par  * NWG * BB + kq * BB + row) * HS;
      #pragma unroll
      for (int s = 0; s < 8; s++) a0[s] = *(const bf16x8*)(h0p + s * 4 * BB * HS);
      #pragma unroll
      for (int s = 0; s < 8; s++) a1[s] = *(const bf16x8*)(h1p + s * 4 * BB * HS);
    }

    // ---- hoisted input loads (hide latency under MFMA) ----
    float x[4];
    #pragma unroll
    for (int j = 0; j < 4; j++) {
      const int ti = p - 3 + j;
      x[j] = (ti >= 0 && doL0) ? y[b_epi * TT + ti] : -100.0f;
    }

    f32x4 acc00 = {0.f,0.f,0.f,0.f}, acc01 = {0.f,0.f,0.f,0.f};
    f32x4 acc10 = {0.f,0.f,0.f,0.f}, acc11 = {0.f,0.f,0.f,0.f};

    if (doL0) {
      #pragma unroll
      for (int s = 0; s < 8; s++) {
        acc00 = __builtin_amdgcn_mfma_f32_16x16x32_bf16(a0[s], w0[0][s], acc00, 0, 0, 0);
        acc01 = __builtin_amdgcn_mfma_f32_16x16x32_bf16(a0[s], w0[1][s], acc01, 0, 0, 0);
      }
    }
    if (doL1) {
      #pragma unroll
      for (int s = 0; s < 8; s++) {
        acc10 = __builtin_amdgcn_mfma_f32_16x16x32_bf16(a0[s], w1[0][s], acc10, 0, 0, 0);
        acc11 = __builtin_amdgcn_mfma_f32_16x16x32_bf16(a0[s], w1[1][s], acc11, 0, 0, 0);
      }
      #pragma unroll
      for (int s = 0; s < 8; s++) {
        acc10 = __builtin_amdgcn_mfma_f32_16x16x32_bf16(a1[s], w1[0][s + 8], acc10, 0, 0, 0);
        acc11 = __builtin_amdgcn_mfma_f32_16x16x32_bf16(a1[s], w1[1][s + 8], acc11, 0, 0, 0);
      }
    }

    // ---- spill gates to LDS (C layout: row=batch=kq*4+j, col=gate-row=ml) ----
    {
      const int bb = wave * 16 + kq * 4;
      if (doL0) {
        #pragma unroll
        for (int j = 0; j < 4; j++) lds_g0[ml     ][bb + j] = acc00[j];
        #pragma unroll
        for (int j = 0; j < 4; j++) lds_g0[16 + ml][bb + j] = acc01[j];
      }
      if (doL1) {
        #pragma unroll
        for (int j = 0; j < 4; j++) lds_g1[ml     ][bb + j] = acc10[j];
        #pragma unroll
        for (int j = 0; j < 4; j++) lds_g1[16 + ml][bb + j] = acc11[j];
      }
    }
    __syncthreads();

    // ---- L0 epilogue: gates -> (c0,h0), publish h0(p) (coalesced strip) ----
    if (doL0) {
      float hn[2];
      #pragma unroll
      for (int e = 0; e < 2; e++) {
        const int d = dl + e;
        const float gi = lds_g0[d     ][b_epi] + s_b0[d     ]
          + s_wih0[d     ][0]*x[0] + s_wih0[d     ][1]*x[1] + s_wih0[d     ][2]*x[2] + s_wih0[d     ][3]*x[3];
        const float gf = lds_g0[8 + d ][b_epi] + s_b0[8 + d ]
          + s_wih0[8 + d ][0]*x[0] + s_wih0[8 + d ][1]*x[1] + s_wih0[8 + d ][2]*x[2] + s_wih0[8 + d ][3]*x[3];
        const float gg = lds_g0[16 + d][b_epi] + s_b0[16 + d]
          + s_wih0[16 + d][0]*x[0] + s_wih0[16 + d][1]*x[1] + s_wih0[16 + d][2]*x[2] + s_wih0[16 + d][3]*x[3];
        const float go = lds_g0[24 + d][b_epi] + s_b0[24 + d]
          + s_wih0[24 + d][0]*x[0] + s_wih0[24 + d][1]*x[1] + s_wih0[24 + d][2]*x[2] + s_wih0[24 + d][3]*x[3];
        const float cn = sigf(gf) * c0[e] + sigf(gi) * tanh_f(gg);
        c0[e] = cn;
        hn[e] = sigf(go) * tanh_f(cn);
      }
      union { __bf16 h[2]; u32 u; } pk;
      pk.h[0] = (__bf16)hn[0]; pk.h[1] = (__bf16)hn[1];
      *(u32*)(h0buf + (par * NWG * BB + w * BB + b_epi) * HS + dl) = pk.u;
    }

    // ---- L1 epilogue: publish h1(p-1) (coalesced strip) ----
    if (doL1) {
      float hn[2];
      #pragma unroll
      for (int e = 0; e < 2; e++) {
        const int d = dl + e;
        const float gi = lds_g1[d     ][b_epi] + s_b1[d     ];
        const float gf = lds_g1[8 + d ][b_epi] + s_b1[8 + d ];
        const float gg = lds_g1[16 + d][b_epi] + s_b1[16 + d];
        const float go = lds_g1[24 + d][b_epi] + s_b1[24 + d];
        const float cn = sigf(gf) * c1[e] + sigf(gi) * tanh_f(gg);
        c1[e] = cn;
        hn[e] = sigf(go) * tanh_f(cn);
      }
      union { __bf16 h[2]; u32 u; } pk;
      pk.h[0] = (__bf16)hn[0]; pk.h[1] = (__bf16)hn[1];
      *(u32*)(h1buf + (parm * NWG * BB + w * BB + b_epi) * HS + dl) = pk.u;
    }

    // ---- barrier publish: drain h stores to L2, then stamp flag ----
    asm volatile("s_waitcnt vmcnt(0)" ::: "memory");
    __syncthreads();
    if (tid == 0)
      __hip_atomic_store(&flags[w * 16], p + 2, __ATOMIC_RELAXED,
                         __HIP_MEMORY_SCOPE_WORKGROUP);   // plain store -> local L2

    // ---- FC output for step p-2 (overlaps flag propagation) ----
    if (p >= 2) {
      const int t = p - 2;
      const int b = 2 * w + (wave & 1);
      const int c = wave >> 1;
      const __bf16* h1r = h1buf + (par * NWG * BB + (lane >> 1) * BB + b) * HS + (lane & 1) * 4;
      union { u64 u; __bf16 h[4]; } c4; c4.u = *(const u64*)h1r;
      float s = 0.f;
      #pragma unroll
      for (int j = 0; j < 4; j++)
        s += (float)c4.h[j] * Wfc[c * HH + lane * 4 + j];
      #pragma unroll
      for (int off = 32; off > 0; off >>= 1) s += __shfl_down(s, off, 64);
      if (lane == 0) out[b * (TT * 2) + t * 2 + c] = s + bfc[c];
    }

    // ---- barrier wait: forced atomic RMW at local TCC (L1-proof) ----
    if (tid < NWG) {
      while (poll_or0_sc0(&flags[tid * 16]) < p + 2) {}
    }
    __syncthreads();
  }
}

extern "C" void kernel_launch(void* const* d_in, const int* in_sizes, int n_in,
                              void* d_out, int out_size, void* d_ws, size_t ws_size,
                              hipStream_t stream) {
  u32* ws = (u32*)d_ws;
  init_ws<<<dim3(64), dim3(256), 0, stream>>>(ws);
  lstm2_persistent<<<dim3(256), dim3(256), 0, stream>>>(
      (const float*)d_in[0],  (const float*)d_in[1], (const float*)d_in[2],
      (const float*)d_in[3],  (const float*)d_in[4], (const float*)d_in[5],
      (const float*)d_in[6],  (const float*)d_in[7], (const float*)d_in[8],
      (const float*)d_in[9],  (const float*)d_in[10],
      (float*)d_out, ws);
}